// Round 10
// baseline (3545.082 us; speedup 1.0000x reference)
//
#include <hip/hip_runtime.h>

// Problem constants (from reference)
#define T_STEPS 100
#define BATCH   32
#define NIN     512
#define NN      2048
#define AREAS   2

// ALPHA = float(np.exp(-1e-3/1e-2)); cast to f32 at use-site.
#define ALPHA_D 0.9048374180359595

// ---------------------------------------------------------------------------
// k0: Poisson input spikes for ALL timesteps. f32 compare semantics.
__global__ __launch_bounds__(256)
void k0_xi(const float* __restrict__ rates, const float* __restrict__ noise,
           float* __restrict__ outXi, unsigned* __restrict__ xi_mask)
{
    int el = blockIdx.x * 256 + threadIdx.x;      // exact grid: 1,638,400
    float r = rates[el], nz = noise[el];
    float p = __fmul_rn(r, 0.001f);
    int spike = (nz < p) ? 1 : 0;
    outXi[el] = (float)spike;
    if (spike) {
        int t = el >> 14;
        int b = (el >> 9) & 31;
        int i = el & (NIN - 1);
        atomicOr(&xi_mask[(t * 32 + b) * 16 + (i >> 5)], 1u << (i & 31));
    }
}

// ---------------------------------------------------------------------------
// k_ff: feedforward currents Iff[t][b][a][n], one block per (tb, a).
__global__ __launch_bounds__(256)
void k_ff(const float* __restrict__ Win, const unsigned* __restrict__ xi_mask,
          float* __restrict__ Iff)
{
    const int tb  = blockIdx.x;      // t*32+b
    const int a   = blockIdx.y;
    const int tid = threadIdx.x;     // cols [8*tid, 8*tid+8)

    __shared__ unsigned mws[16];
    if (tid < 16) mws[tid] = xi_mask[tb * 16 + tid];
    __syncthreads();

    const float* Wa = Win + ((size_t)a << 20) + (tid << 3);
    float4 A0 = {0,0,0,0}, A1 = {0,0,0,0};
    for (int w = 0; w < 16; ++w) {
        unsigned mw = mws[w];
        int base_i = w << 5;
        while (mw) {
            int i = base_i + (__ffs(mw) - 1);
            mw &= mw - 1;
            const float* rp = Wa + ((size_t)i << 11);
            float4 w0 = ((const float4*)rp)[0];
            float4 w1 = ((const float4*)rp)[1];
            A0.x += w0.x; A0.y += w0.y; A0.z += w0.z; A0.w += w0.w;
            A1.x += w1.x; A1.y += w1.y; A1.z += w1.z; A1.w += w1.w;
        }
    }
    float* op = Iff + (((size_t)tb * 2 + a) << 11) + (tid << 3);
    ((float4*)op)[0] = A0;
    ((float4*)op)[1] = A1;
}

// ---------------------------------------------------------------------------
#define OFF_OF(rr) ((((rr) >> 11) << 23) + (((rr) & 2047) << 11))

// global -> LDS direct staging: one instruction stages 64 lanes x 16B = 1KB,
// counted by vmcnt, ZERO VGPRs held. src per-lane, dst wave-uniform.
#define GLDS(src, dst) __builtin_amdgcn_global_load_lds(                      \
    (const __attribute__((address_space(1))) void*)(src),                     \
    (__attribute__((address_space(3))) void*)(dst), 16, 0, 0)

// issue 4 rows (1KB each) of this wave's column slice into dstbase
#define ISSUE4(lp4, dstbase) do {                                             \
    GLDS(Wb + OFF_OF((int)(lp4)[0]), (dstbase));                              \
    GLDS(Wb + OFF_OF((int)(lp4)[1]), (dstbase) + 256);                        \
    GLDS(Wb + OFF_OF((int)(lp4)[2]), (dstbase) + 512);                        \
    GLDS(Wb + OFF_OF((int)(lp4)[3]), (dstbase) + 768);                        \
} while (0)

#define ACC4(P)  { acc.x = __fadd_rn(acc.x, (P).x); acc.y = __fadd_rn(acc.y, (P).y); \
                   acc.z = __fadd_rn(acc.z, (P).z); acc.w = __fadd_rn(acc.w, (P).w); }

// ---------------------------------------------------------------------------
// k_steps v10: ONE BLOCK PER BATCH (32 blocks x 1024 thr = 16 waves), all
// spike exchange in LDS. Post-mortem chain (us/step):
//   R0 14.5 | R2 33.7 | v3 16.7 | v4 12.1 | v5 10.6 | v6 9.6 | v7 10.7 |
//   v8 WRONG | v9 12.3.
// v9's decisive negative: GLDS made the gather ~1us (25 coalesced 1KB
// fire-and-forget loads + one vmcnt), yet the step REGRESSED -> the ~10us
// floor is the cross-block fabric chain (5-7 serial loaded RTs ~1.5us:
// exch->CP, poll detect, per-step Iff/outS), not the gather. R2's failure
// was never sync either: it was register-gather BW (compiler caps ~5
// outstanding/lane -> 41 GB/s/CU). m56 measured 144 GB/s/CU pull at 16
// waves/CU; m97 GEMM proves GLDS sustains >>55 GB/s/CU staging. So: R2's
// topology (zero fabric hops, 3 __syncthreads/step, zero global atomics,
// plain launch) + v9's GLDS gather (per-wave double-buffered rounds of
// 4 rows x 1KB, vmcnt(4) counted waits, rule-#18 fences).
// Thread tid: area a=tid>>9; wave w=tid>>6 covers cols [(w&7)*256, +256)
// of area w>>3; lane's 4 cols c=(w&7)*256+lane*4. Gather consume order:
// STRICTLY ascending global row (s,n), serial __fadd_rn per column --
// bit-exact (same order R2 validated, absmax 0.0).
__global__ __launch_bounds__(1024, 1)
void k_steps(const float* __restrict__ Wrec,
             const float* __restrict__ Iff,     // [t][b][a][n]
             float* __restrict__ outS)          // out + T*B*NIN
{
    const int tid  = threadIdx.x;              // 0..1023
    const int b    = blockIdx.x;               // batch
    const int w    = tid >> 6;                 // wave 0..15
    const int lane = tid & 63;
    const int a    = w >> 3;                   // dst area
    const int c    = ((w & 7) << 8) + (lane << 2);  // lane's 4 dst cols

    __shared__ __align__(16) float stage[16 * 2048];          // 128 KB
    __shared__ unsigned msk[2][128];           // double-buffered spike masks
    __shared__ int base[128];
    __shared__ __align__(16) unsigned short lrec[4100];       // +3 pad slots
    __shared__ int cnt_rec;

    const float* __restrict__ Wb = Wrec + ((size_t)a << 22) + c;
    float* const myStage = &stage[w << 11];    // 2 bufs x 4 rows x 256 f32
    const int rr_self = (a << 11) | c;
    const int wsel = rr_self >> 5;
    const int bsh  = rr_self & 31;             // nibble-aligned (c = 4k)

    if (tid < 128) msk[0][tid] = 0u;           // Xd(t=-1) = 0
    __syncthreads();

    float4 vst = {0.f, 0.f, 0.f, 0.f};

    for (int t = 0; t < T_STEPS; ++t) {
        unsigned* cm = msk[t & 1];             // spikes from t-1 (= Xd)
        unsigned* nm = msk[(t + 1) & 1];       // spikes produced at t

        // feedforward current: issue early, RT hides under scan/expand
        float4 accf = *(const float4*)
            &Iff[((((size_t)t * BATCH + b) * 2 + a) << 11) + c];

        // ---- phase 1: zero next-mask; wave-0 prefix scan of cm
        if (tid < 128) nm[tid] = 0u;
        if (tid < 64) {
            int c0 = __popc(cm[2 * tid]), c1 = __popc(cm[2 * tid + 1]);
            int cc = c0 + c1, incl = cc;
            #pragma unroll
            for (int d = 1; d < 64; d <<= 1) {
                int v = __shfl_up(incl, d, 64);
                if (tid >= d) incl += v;
            }
            base[2 * tid]     = incl - cc;
            base[2 * tid + 1] = incl - c1;
            if (tid == 63) cnt_rec = incl;
        }
        __syncthreads();

        // ---- phase 2: expand cm to ascending row list + pad to mult of 4
        if (tid < 128) {
            unsigned wd = cm[tid];
            if (wd) {
                int off = base[tid];
                int bb = tid << 5;
                while (wd) {
                    int p = __ffs(wd) - 1;
                    lrec[off++] = (unsigned short)(bb + p);
                    wd &= wd - 1;
                }
            }
        }
        if (tid == 0) {                        // pad slots (row 0 = valid addr)
            int nr = cnt_rec;
            lrec[nr] = 0; lrec[nr + 1] = 0; lrec[nr + 2] = 0;
        }
        __syncthreads();

        const int nrec = cnt_rec;
        unsigned xw = (cm[wsel] >> bsh) & 0xFu;

        // ---- phase 3: per-wave GLDS gather, double-buffered rounds of 4
        //      rows x 1KB. vmcnt counted waits (conservative with older
        //      accf/outS ops in flight: vmcnt retires in order). Consume
        //      ascending rows, serial __fadd_rn per column (bit-exact).
        float4 acc = {0.f, 0.f, 0.f, 0.f};
        if (nrec > 0) {
            const int nr4 = (nrec + 3) >> 2;
            ISSUE4(&lrec[0], myStage);
            for (int r = 0; r < nr4; ++r) {
                if (r + 1 < nr4) {
                    ISSUE4(&lrec[(r + 1) << 2],
                           myStage + (((r + 1) & 1) << 10));
                    asm volatile("s_waitcnt vmcnt(4)");
                } else {
                    asm volatile("s_waitcnt vmcnt(0)");
                }
                __builtin_amdgcn_sched_barrier(0);     // rule #18 fence
                const float* cb = myStage + ((r & 1) << 10);
                int lim = nrec - (r << 2); if (lim > 4) lim = 4;
                if (lim == 4) {
                    float4 w0 = *(const float4*)(cb + (lane << 2));
                    float4 w1 = *(const float4*)(cb + 256 + (lane << 2));
                    float4 w2 = *(const float4*)(cb + 512 + (lane << 2));
                    float4 w3 = *(const float4*)(cb + 768 + (lane << 2));
                    ACC4(w0); ACC4(w1); ACC4(w2); ACC4(w3);
                } else {
                    for (int k = 0; k < lim; ++k) {
                        float4 wv = *(const float4*)(cb + (k << 8) + (lane << 2));
                        ACC4(wv);
                    }
                }
                __builtin_amdgcn_sched_barrier(0);     // pin consume before
            }                                          // next-round issue
        }

        // ---- phase 4: LIF update, numpy f32 op-for-op ----
        float4 sv;
        unsigned nib = 0u;
#define LIF(K, BIT) { \
            float v  = __fmul_rn((float)ALPHA_D, vst.K); \
            if (xw & BIT) v = 0.0f; \
            float I  = __fadd_rn(accf.K, acc.K); \
            float vn = __fadd_rn(v, I); \
            vst.K = vn; \
            if (vn >= 1.0f) { sv.K = 1.0f; nib |= BIT; } else sv.K = 0.0f; \
        }
        LIF(x, 1u) LIF(y, 2u) LIF(z, 4u) LIF(w, 8u)
#undef LIF
        *(float4*)&outS[(size_t)a * (T_STEPS * BATCH * NN)
                        + (((size_t)t * BATCH + b) << 11) + c] = sv;
        if (nib) atomicOr(&nm[wsel], nib << bsh);      // LDS atomic

        __syncthreads();    // spikes(t) complete before next step's scan
    }
}
#undef OFF_OF
#undef ACC4
#undef ISSUE4
#undef GLDS

// ---------------------------------------------------------------------------
extern "C" void kernel_launch(void* const* d_in, const int* in_sizes, int n_in,
                              void* d_out, int out_size, void* d_ws, size_t ws_size,
                              hipStream_t stream)
{
    const float* rates = (const float*)d_in[0];
    const float* noise = (const float*)d_in[1];
    const float* Win   = (const float*)d_in[2];
    const float* Wrec  = (const float*)d_in[3];
    float* out = (float*)d_out;

    // workspace layout (bytes):
    //   [0, 204800)           xi_mask uint32[T][B][16]
    //   [204800, +52428800)   Iff     float[T][B][A][N]  (16B aligned)
    char* ws = (char*)d_ws;
    unsigned* xi_mask = (unsigned*)ws;
    float* Iff = (float*)(ws + 204800);

    hipMemsetAsync(d_ws, 0, 204800, stream);   // zero xi_mask

    k0_xi<<<6400, 256, 0, stream>>>(rates, noise, out, xi_mask);
    k_ff<<<dim3(3200, 2), 256, 0, stream>>>(Win, xi_mask, Iff);

    float* outS = out + (size_t)T_STEPS * BATCH * NIN;
    k_steps<<<32, 1024, 0, stream>>>(Wrec, Iff, outS);
}

// Round 11
// 1089.736 us; speedup vs baseline: 3.2532x; 3.2532x over previous
//
#include <hip/hip_runtime.h>

// Problem constants (from reference)
#define T_STEPS 100
#define BATCH   32
#define NIN     512
#define NN      2048
#define AREAS   2

// ALPHA = float(np.exp(-1e-3/1e-2)); cast to f32 at use-site.
#define ALPHA_D 0.9048374180359595

// ---------------------------------------------------------------------------
// k0: Poisson input spikes for ALL timesteps. f32 compare semantics.
__global__ __launch_bounds__(256)
void k0_xi(const float* __restrict__ rates, const float* __restrict__ noise,
           float* __restrict__ outXi, unsigned* __restrict__ xi_mask)
{
    int el = blockIdx.x * 256 + threadIdx.x;      // exact grid: 1,638,400
    float r = rates[el], nz = noise[el];
    float p = __fmul_rn(r, 0.001f);
    int spike = (nz < p) ? 1 : 0;
    outXi[el] = (float)spike;
    if (spike) {
        int t = el >> 14;
        int b = (el >> 9) & 31;
        int i = el & (NIN - 1);
        atomicOr(&xi_mask[(t * 32 + b) * 16 + (i >> 5)], 1u << (i & 31));
    }
}

// ---------------------------------------------------------------------------
// k_ff: feedforward currents Iff[t][b][a][n], one block per (tb, a).
__global__ __launch_bounds__(256)
void k_ff(const float* __restrict__ Win, const unsigned* __restrict__ xi_mask,
          float* __restrict__ Iff)
{
    const int tb  = blockIdx.x;      // t*32+b
    const int a   = blockIdx.y;
    const int tid = threadIdx.x;     // cols [8*tid, 8*tid+8)

    __shared__ unsigned mws[16];
    if (tid < 16) mws[tid] = xi_mask[tb * 16 + tid];
    __syncthreads();

    const float* Wa = Win + ((size_t)a << 20) + (tid << 3);
    float4 A0 = {0,0,0,0}, A1 = {0,0,0,0};
    for (int w = 0; w < 16; ++w) {
        unsigned mw = mws[w];
        int base_i = w << 5;
        while (mw) {
            int i = base_i + (__ffs(mw) - 1);
            mw &= mw - 1;
            const float* rp = Wa + ((size_t)i << 11);
            float4 w0 = ((const float4*)rp)[0];
            float4 w1 = ((const float4*)rp)[1];
            A0.x += w0.x; A0.y += w0.y; A0.z += w0.z; A0.w += w0.w;
            A1.x += w1.x; A1.y += w1.y; A1.z += w1.z; A1.w += w1.w;
        }
    }
    float* op = Iff + (((size_t)tb * 2 + a) << 11) + (tid << 3);
    ((float4*)op)[0] = A0;
    ((float4*)op)[1] = A1;
}

// ---------------------------------------------------------------------------
#define OFF_OF(rr) ((((rr) >> 11) << 23) + (((rr) & 2047) << 11))

// global -> LDS direct staging: one instruction stages 64 lanes x 16B = 1KB
// (this block's full 256-col slice of one Wrec row), vmcnt-counted, zero
// VGPRs held. Global src per-lane, LDS dst wave-uniform.
#define GLDS(src, dst) __builtin_amdgcn_global_load_lds(                      \
    (const __attribute__((address_space(1))) void*)(src),                     \
    (__attribute__((address_space(3))) void*)(dst), 16, 0, 0)

// ---------------------------------------------------------------------------
// k_steps v11: 512 blocks = 32 batches x 16 column-slices, 256 threads
// (1 dst col/thread). Post-mortem chain (us/step):
//   R0 14.5 | R2 33.7 | v3 16.7 | v4 12.1 | v5 10.6 | v6 9.6 | v7 10.7 |
//   v8 WRONG | v9 12.3 | v10 34.2.
// v10's counters settled three questions: (1) per-CU fill ceiling ~41
// GB/s/CU is real (R2 registers = v10 GLDS, both 16 waves/CU); (2) the
// 16-slice XCD-pinned layout is what buys FETCH 1.29GB vs 4.48GB (3.5x
// L2/L3 dedup) -- one-block-per-batch is structurally dead (32 CUs x 41
// GB/s < 44.8 MB/step); (3) v10's depth-2 4KB rounds self-serialized
// (~22 RT = 33us). v6 (best, 9.6) never passed 18 GB/s/CU: register-C
// capped. v11 = v6's topology + sync, with the gather replaced by v9's
// proven burst-GLDS: per round the 4 waves stage up to 64 rows x 1KB
// (wave w takes slots k%4==w, ~16 fire-and-forget GLDS each, 64KB in
// flight/block), one vmcnt(0)+__syncthreads drain, then 256 threads
// consume stride-1 from LDS (bank-conflict-free) in STRICTLY ascending
// row order with serial __fadd_rn per column -- v6's exact add sequence,
// bit-exact. Typical nrec~87 => 2 rounds => gather ~max(2RT~3us,
// 174KB/CU / 41GB/s ~ 4.3us) vs v6's ~7-8us trickle.
// LDS: 64KB stage + ~9KB = 74.8KB -> exactly 2 blocks/CU (8 waves).
// Sync = v5/v6 data-is-the-barrier (epoch-tagged u64 masks, atomicExch
// publish at CP, coalesced agent-scope poll; proven in 3 passing rounds).
__global__ __launch_bounds__(256, 2)
void k_steps(const float* __restrict__ Wrec,
             unsigned long long* __restrict__ smask,  // [2][B][128] u64 tag|mask
             const float* __restrict__ Iff,           // [t][b][a][n]
             float* __restrict__ outS)                // out + T*B*NIN
{
    const int tid = threadIdx.x;               // 0..255
    const int bx  = blockIdx.x;                // b*16 + s  (XCD = s%8)
    const int s   = bx & 15;
    const int b   = bx >> 4;
    const int a   = s >> 3;                    // dst area
    const int m0  = (s & 7) << 8;              // column-slice base
    const int c   = m0 + tid;                  // this thread's dst column
    const int wv  = tid >> 6;                  // wave 0..3
    const int lane = tid & 63;

    __shared__ __align__(16) float stage[64 * 256];            // 64 KB
    __shared__ unsigned mws[128];
    __shared__ __align__(16) unsigned short lrec[AREAS * NN];  // 8 KB
    __shared__ int base[128];
    __shared__ int cnt_rec;
    __shared__ unsigned nsp[8];

    // per-lane global src base: lane covers 16B (4 cols) of the block slice
    const float* __restrict__ Wb = Wrec + ((size_t)a << 22) + m0 + (lane << 2);
    const int rr_self = (a << 11) | c;
    const int wsel = rr_self >> 5;
    const int w0   = s << 3;                   // this block's 8 owned words

    float vst = 0.0f;

    for (int t = 0; t < T_STEPS; ++t) {
        unsigned long long* cur = smask + (size_t)(t & 1) * (BATCH * 128) + (b << 7);
        unsigned long long* nxt = smask + (size_t)((t + 1) & 1) * (BATCH * 128) + (b << 7);

        // ---- phase 1: data-spin -- each of 128 lanes polls its own
        //      tagged word (coalesced agent-scope loads, one RT to detect)
        if (tid < 128) {
            unsigned long long v = __hip_atomic_load(&cur[tid], __ATOMIC_RELAXED,
                                                     __HIP_MEMORY_SCOPE_AGENT);
            while ((unsigned)(v >> 32) != (unsigned)t) {
                __builtin_amdgcn_s_sleep(4);
                v = __hip_atomic_load(&cur[tid], __ATOMIC_RELAXED,
                                      __HIP_MEMORY_SCOPE_AGENT);
            }
            mws[tid] = (unsigned)v;
        }
        if (tid < 8) nsp[tid] = 0u;
        float accf = Iff[((((size_t)t * BATCH + b) * 2 + a) << 11) + c];
        __syncthreads();

        // ---- phase 2: wave-0 prefix scan of mask popcounts
        if (tid < 64) {
            int c0 = __popc(mws[2 * tid]), c1 = __popc(mws[2 * tid + 1]);
            int cc = c0 + c1, incl = cc;
            #pragma unroll
            for (int d = 1; d < 64; d <<= 1) {
                int v = __shfl_up(incl, d, 64);
                if (tid >= d) incl += v;
            }
            base[2 * tid]     = incl - cc;
            base[2 * tid + 1] = incl - c1;
            if (tid == 63) cnt_rec = incl;
        }
        __syncthreads();

        // ---- phase 3: expand mask to ascending row list
        if (tid < 128) {
            unsigned w = mws[tid];
            if (w) {
                int off = base[tid];
                int bb = tid << 5;
                while (w) {
                    int p = __ffs(w) - 1;
                    lrec[off++] = (unsigned short)(bb + p);
                    w &= w - 1;
                }
            }
        }
        __syncthreads();

        const int nrec = cnt_rec;
        unsigned xd = (mws[wsel] >> (tid & 31)) & 1u;

        // ---- phase 4: burst-GLDS gather, rounds of <=64 rows x 1KB.
        //      Issue: wave wv stages slots k%4==wv, fire-and-forget (zero
        //      VGPRs held, 64KB/block in flight). Drain once, consume
        //      stride-1 from LDS (conflict-free), STRICTLY ascending row
        //      order, serial __fadd_rn per column (bit-exact). -----------
        float accr = 0.0f;
        for (int j = 0; j < nrec; j += 64) {
            const int cnt = min(64, nrec - j);
            for (int k = wv; k < cnt; k += 4) {
                int row = lrec[j + k];
                GLDS(Wb + OFF_OF(row), &stage[k << 8]);
            }
            asm volatile("s_waitcnt vmcnt(0)" ::: "memory");   // rows landed
            __builtin_amdgcn_sched_barrier(0);                 // rule #18
            __syncthreads();                   // all waves' slots visible
            int k = 0;
            for (; k + 4 <= cnt; k += 4) {
                float w0v = stage[((k + 0) << 8) + tid];
                float w1v = stage[((k + 1) << 8) + tid];
                float w2v = stage[((k + 2) << 8) + tid];
                float w3v = stage[((k + 3) << 8) + tid];
                accr = __fadd_rn(accr, w0v);
                accr = __fadd_rn(accr, w1v);
                accr = __fadd_rn(accr, w2v);
                accr = __fadd_rn(accr, w3v);
            }
            for (; k < cnt; ++k)
                accr = __fadd_rn(accr, stage[(k << 8) + tid]);
            __syncthreads();                   // done reading before reuse
        }

        // ---- phase 5: LIF update, numpy f32 op-for-op ----
        float I  = __fadd_rn(accf, accr);
        float v  = __fmul_rn((float)ALPHA_D, vst);
        if (xd) v = 0.0f;
        float vn = __fadd_rn(v, I);
        vst = vn;
        int S = (vn >= 1.0f) ? 1 : 0;
        if (S) atomicOr(&nsp[tid >> 5], 1u << (tid & 31));
        __syncthreads();                       // nsp complete

        // ---- phase 6: publish tagged words FIRST, then outS store
        if (t < T_STEPS - 1 && tid < 8) {
            unsigned long long pv =
                ((unsigned long long)(unsigned)(t + 1) << 32) | nsp[tid];
            atomicExch(&nxt[w0 + tid], pv);    // RMW executes at CP (m20)
        }
        outS[(size_t)a * (T_STEPS * BATCH * NN)
             + (((size_t)t * BATCH + b) << 11) + c] = (float)S;
    }
}
#undef OFF_OF
#undef GLDS

// ---------------------------------------------------------------------------
extern "C" void kernel_launch(void* const* d_in, const int* in_sizes, int n_in,
                              void* d_out, int out_size, void* d_ws, size_t ws_size,
                              hipStream_t stream)
{
    const float* rates = (const float*)d_in[0];
    const float* noise = (const float*)d_in[1];
    const float* Win   = (const float*)d_in[2];
    const float* Wrec  = (const float*)d_in[3];
    float* out = (float*)d_out;

    // workspace layout (bytes):
    //   [0, 204800)           xi_mask uint32[T][B][16]
    //   [204800, 270336)      smask   u64[2][B][128]  (tag<<32 | mask)
    //   [270336, +52428800)   Iff     float[T][B][A][N]  (16B aligned)
    char* ws = (char*)d_ws;
    unsigned* xi_mask = (unsigned*)ws;
    unsigned long long* smask = (unsigned long long*)(ws + 204800);
    float* Iff = (float*)(ws + 270336);

    hipMemsetAsync(d_ws, 0, 270336, stream);   // zero xi_mask + smask

    k0_xi<<<6400, 256, 0, stream>>>(rates, noise, out, xi_mask);
    k_ff<<<dim3(3200, 2), 256, 0, stream>>>(Win, xi_mask, Iff);

    float* outS = out + (size_t)T_STEPS * BATCH * NIN;
    void* args[] = { (void*)&Wrec, (void*)&smask, (void*)&Iff, (void*)&outS };
    hipLaunchCooperativeKernel((const void*)k_steps, dim3(512), dim3(256),
                               args, 0, stream);
}